// Round 5
// baseline (166.989 us; speedup 1.0000x reference)
//
#include <hip/hip_runtime.h>

// NeuSSampler PDF importance resampling — convergent query-parallel via LDS
// inversion table, 4 rays per wave with prefetched loads.
//
// Per ray (one wave, wave-synchronous, no __syncthreads):
//  1. lane l owns weights/bins pair (2l, 2l+1); pair-sum DPP inclusive scan
//     -> cdf edges c[2l+1], c[2l+2] in registers (monotone by construction).
//  2. entries (cdf[k], bins[k]) k=0..128 staged to LDS.
//  3. inversion: seg[j] = max{k : jf(c_k) == j}, jf(c)=ceil(65c-0.5) = first
//     query with u_j >= c. Scatter k via atomicMax (init 0 = edge 0), then a
//     6-step DPP max-scan gives k*(j) = max{k : cdf[k] <= u_j} — exactly
//     searchsorted_right(cdf, u_j) - 1. No search, no divergent loops.
//  4. lane j gathers entries k*, min(k*+1,128), interpolates, coalesced
//     store. Query 64 computed uniformly (broadcast reads), stored by lane 0.
//
// Degenerate cases: cdf[k*+1] > u_j by maximality, so d > 0 except the
// clipped k*=128 case where bins coincide; 0*inf=NaN -> fmaxf(NaN,0)=0
// (IEEE maxNum) reproduces the reference's nan_to_num -> 0.
//
// Latency: 4 rays' global loads issued before any compute (one HBM wait
// amortized 4x); LDS double-buffered by ray parity so chains overlap.
// DS pipe is in-order per wave; wave_barrier/lgkm fences pin compiler order
// without draining vmcnt (prefetches stay in flight).

#define DPP_FADD(x, ctrl, rmask)                                             \
    ((x) + __int_as_float(__builtin_amdgcn_update_dpp(                       \
               0, __float_as_int(x), (ctrl), (rmask), 0xf, true)))

#define DPP_IMAX(x, ctrl, rmask)                                             \
    do {                                                                     \
        int _y = __builtin_amdgcn_update_dpp(0, (x), (ctrl), (rmask), 0xf,   \
                                             true);                          \
        (x) = (x) > _y ? (x) : _y;                                           \
    } while (0)

__device__ __forceinline__ void lds_fence() {
    // lgkmcnt(0) only: vmcnt=0x3F, expcnt=7 untouched -> prefetches unharmed
    __builtin_amdgcn_s_waitcnt(0xC07F);
    __builtin_amdgcn_wave_barrier();
}

__global__ __launch_bounds__(256, 8) void neus_sampler_kernel(
    const float* __restrict__ weights,
    const float* __restrict__ bins_g,
    const float* __restrict__ nears,
    const float* __restrict__ fars,
    float* __restrict__ out,
    int R)
{
    constexpr int S  = 128;   // weights per ray
    constexpr int SE = 129;   // bin edges per ray
    constexpr int NB = 65;    // output samples per ray
    constexpr int NR = 4;     // rays per wave
    constexpr float HPAD = 1e-5f;

    __shared__ float s_cdf[4][2][132];
    __shared__ float s_bin[4][2][132];
    __shared__ int   s_seg[4][2][68];

    const int lane = threadIdx.x & 63;
    const int wv   = threadIdx.x >> 6;
    const int uw   = __builtin_amdgcn_readfirstlane(blockIdx.x * 4 + wv);
    const int base = uw * NR;
    if (base >= R) return;                       // wave-uniform exit

    // ---- prefetch all 4 rays' inputs (independent loads, one HBM wait) ----
    float2 W[NR], B[NR];
    float  BL[NR], NE[NR], FA[NR];               // uniform -> SGPR
    #pragma unroll
    for (int i = 0; i < NR; ++i) {
        int r = base + i; r = r < R ? r : R - 1;
        W[i] = reinterpret_cast<const float2*>(weights + (size_t)r * S)[lane];
        const float* brow = bins_g + (size_t)r * SE;
        B[i]  = reinterpret_cast<const float2*>(brow)[lane];
        BL[i] = brow[S];
        NE[i] = nears[r];
        FA[i] = fars[r];
    }

    // first query index j with u_j >= c  (u_j = (2j+1)/130)
    auto jf = [](float c) -> int {
        int j = (int)ceilf(fmaf(65.0f, c, -0.5f));
        return j < 0 ? 0 : (j > NB ? NB : j);
    };

    #pragma unroll
    for (int i = 0; i < NR; ++i) {
        const int ray = base + i;
        const bool ok = ray < R;
        float* cdfb = s_cdf[wv][i & 1];
        float* binb = s_bin[wv][i & 1];
        int*   segb = s_seg[wv][i & 1];

        // ---- init inversion table (edge 0 -> k=0 covered by the zeros) ----
        segb[lane] = 0;
        if (lane == 0) segb[64] = 0;

        // ---- cdf edges: pair-sum DPP inclusive scan ----
        const float w1 = W[i].y + HPAD;
        float ps = (W[i].x + HPAD) + w1;
        ps = DPP_FADD(ps, 0x111, 0xf);  // row_shr:1
        ps = DPP_FADD(ps, 0x112, 0xf);  // row_shr:2
        ps = DPP_FADD(ps, 0x114, 0xf);  // row_shr:4
        ps = DPP_FADD(ps, 0x118, 0xf);  // row_shr:8
        ps = DPP_FADD(ps, 0x142, 0xa);  // row_bcast:15 -> rows 1,3
        ps = DPP_FADD(ps, 0x143, 0xc);  // row_bcast:31 -> rows 2,3

        const float total = __int_as_float(
            __builtin_amdgcn_readlane(__float_as_int(ps), 63));
        const float padding = fmaxf(1e-5f - total, 0.0f);  // relu(EPS - sum)
        const float padc    = padding * (1.0f / S);
        const float inv     = __builtin_amdgcn_rcpf(total + padding);

        const float c_hi  = fminf(1.0f, fmaf((float)(2*lane+2), padc, ps) * inv);
        const float c_mid = fminf(1.0f, fmaf((float)(2*lane+1), padc, ps - w1) * inv);
        float b2 = __shfl_down(B[i].x, 1, 64);   // bins[2l+2]
        if (lane == 63) b2 = BL[i];              // bins[128]

        // ---- stage entries: cdf[k], bins[k], k = 0..128 ----
        cdfb[2*lane+1] = c_mid;
        cdfb[2*lane+2] = c_hi;
        binb[2*lane+1] = B[i].y;
        binb[2*lane+2] = b2;
        if (lane == 0) { cdfb[0] = 0.0f; binb[0] = B[i].x; }

        __builtin_amdgcn_wave_barrier();         // init before atomics

        // ---- scatter: seg[jf(c_k)] = max k (edges 1..128) ----
        const int jm = jf(c_mid);
        const int jh = jf(c_hi);
        if (jm < NB) atomicMax(&segb[jm], 2*lane+1);
        if (jh < NB) atomicMax(&segb[jh], 2*lane+2);

        lds_fence();                             // scatter done before scan

        // ---- max-scan: k*(j) = max{k : cdf[k] <= u_j} ----
        int k = segb[lane];
        DPP_IMAX(k, 0x111, 0xf);
        DPP_IMAX(k, 0x112, 0xf);
        DPP_IMAX(k, 0x114, 0xf);
        DPP_IMAX(k, 0x118, 0xf);
        DPP_IMAX(k, 0x142, 0xa);
        DPP_IMAX(k, 0x143, 0xc);
        const int k63 = __builtin_amdgcn_readlane(k, 63);
        const int s64 = segb[64];                // broadcast read
        const int k64 = k63 > s64 ? k63 : s64;

        // ---- gather + interpolate ----
        const float fmn = FA[i] - NE[i];
        auto interp = [&](int kk, float u) -> float {
            const int kb = (kk + 1 > S) ? S : kk + 1;   // clip 'above' to 128
            const float c0 = cdfb[kk], c1 = cdfb[kb];
            const float b0 = binb[kk], b1 = binb[kb];
            float t = (u - c0) * __builtin_amdgcn_rcpf(c1 - c0);
            t = fminf(fmaxf(t, 0.0f), 1.0f);            // NaN-safe -> 0
            return fmaf(fmaf(t, b1 - b0, b0), fmn, NE[i]);
        };

        const float res = interp(k,   (float)(2*lane+1) * (1.0f / 130.0f));
        const float r64 = interp(k64, 129.0f * (1.0f / 130.0f));  // uniform

        if (ok) {
            float* orow = out + (size_t)ray * NB;
            orow[lane] = res;                    // coalesced
            if (lane == 0) orow[NB - 1] = r64;
        }
    }
}

extern "C" void kernel_launch(void* const* d_in, const int* in_sizes, int n_in,
                              void* d_out, int out_size, void* d_ws, size_t ws_size,
                              hipStream_t stream) {
    const float* weights = (const float*)d_in[0];   // [R,128,1]
    const float* ebins   = (const float*)d_in[1];   // [R,129]
    const float* nears   = (const float*)d_in[2];   // [R,1]
    const float* fars    = (const float*)d_in[3];   // [R,1]
    float* out = (float*)d_out;                     // [R,65]
    const int R = in_sizes[0] / 128;
    const int rays_per_block = 4 * 4;               // 4 waves x 4 rays
    const int blocks = (R + rays_per_block - 1) / rays_per_block;
    hipLaunchKernelGGL(neus_sampler_kernel, dim3(blocks), dim3(256), 0, stream,
                       weights, ebins, nears, fars, out, R);
}